// Round 5
// baseline (219.472 us; speedup 1.0000x reference)
//
#include <hip/hip_runtime.h>
#include <hip/hip_fp16.h>
#include <math.h>

typedef _Float16 f16;
typedef f16 f16x8 __attribute__((ext_vector_type(8)));
typedef float f32x4 __attribute__((ext_vector_type(4)));

#define B_ 4
#define C_ 64
#define L_ 4096
#define N_ 100000
#define P_ (B_ * N_)
#define NEG 0.2f

static __device__ __forceinline__ f32x4 mfma16(f16x8 a, f16x8 b, f32x4 c) {
    return __builtin_amdgcn_mfma_f32_16x16x32_f16(a, b, c, 0, 0, 0);
}
static __device__ __forceinline__ f16x8 splat8(f16 x) {
    f16x8 v = {x, x, x, x, x, x, x, x};
    return v;
}

// ---------- kernel 1: transpose feat (B,C,L) f32 -> (B,L,C) f16 ----------
__global__ void transpose_feat(const float* __restrict__ src, f16* __restrict__ dst) {
    __shared__ float tile[64][65];
    const int b  = blockIdx.y;
    const int l0 = blockIdx.x * 64;
    const int tx = threadIdx.x & 63;
    const int ty = threadIdx.x >> 6;   // 0..3
    const size_t base = (size_t)b * C_ * L_;
    #pragma unroll
    for (int cc = ty; cc < 64; cc += 4)
        tile[cc][tx] = src[base + (size_t)cc * L_ + l0 + tx];
    __syncthreads();
    // writers: 4B per lane (two f16 channels), banks 2-way (free)
    const int c2 = (threadIdx.x & 31) * 2;
    const int lh = (threadIdx.x >> 5) & 1;
    #pragma unroll
    for (int l8 = 0; l8 < 64; l8 += 8) {
        const int row = l8 + ty * 2 + lh;
        union { f16 h[2]; unsigned u; } pk;
        pk.h[0] = (f16)tile[c2][row];
        pk.h[1] = (f16)tile[c2 + 1][row];
        *(unsigned*)(dst + base + ((size_t)(l0 + row) << 6) + c2) = pk.u;
    }
}

// ---------- kernel 2: pack W1/Wr/W2 into per-lane f16 MFMA B-fragments ----------
__global__ void pack_weights(const float* __restrict__ W1, const float* __restrict__ Wr,
                             const float* __restrict__ W2,
                             f16* __restrict__ W1f, f16* __restrict__ Wrf, f16* __restrict__ W2f) {
    int i = blockIdx.x * 256 + threadIdx.x;
    if (i < 4096) {
        int e = i & 7, lane = (i >> 3) & 63, ks = (i >> 9) & 1, nt = i >> 10;
        int k = ks * 32 + (lane >> 4) * 8 + e;
        int c = nt * 16 + (lane & 15);
        W1f[i] = (f16)W1[k * 64 + c];
        Wrf[i] = (f16)Wr[k * 64 + c];
    }
    if (i < 1024) {                       // W2 padded 64x10 -> 64x16
        int e = i & 7, lane = (i >> 3) & 63, ks = (i >> 9) & 1;
        int k = ks * 32 + (lane >> 4) * 8 + e;
        int c = lane & 15;
        W2f[i] = (c < 10) ? (f16)W2[k * 10 + c] : (f16)0.0f;
    }
}

// ---------- kernel 3: router MLP via MFMA; writes tap-major xq / wk ----------
// one wave = 16 points. A-layout: lane -> row r=l&15, k=(l>>4)*8+e.
// C-layout (HW-verified): lane -> col=l&15, row=(l>>4)*4+reg.
__global__ __launch_bounds__(256) void mlp_mfma(
    const f16* __restrict__ featT, const float* __restrict__ coords,
    const f16* __restrict__ W1f, const f16* __restrict__ Wrf, const f16* __restrict__ W2f,
    const float* __restrict__ W1, const float* __restrict__ b1,
    const float* __restrict__ br, const float* __restrict__ b2,
    float* __restrict__ xq_arr, float* __restrict__ wk_arr)
{
    __shared__ __align__(16) f16 a_tile[4][16][72];   // per-wave staging, no barriers

    const int tid = threadIdx.x;
    const int wv  = tid >> 6;
    const int l   = tid & 63;
    const int r   = l & 15;
    const int q   = l >> 4;
    const int col = l & 15;
    const int p0  = (blockIdx.x * 4 + wv) * 16;
    const int p   = p0 + r;
    const int b   = p / N_;

    // ---- anchor position for this lane's A-role point ----
    const float cx = coords[p];
    float xp = fminf(fmaxf((cx + 1.0f) * 0.5f * 4095.0f, 0.0f), 4095.0f);
    float x0f = floorf(xp);
    float w = xp - x0f;
    int i0 = (int)x0f;
    int i1 = min(i0 + 1, 4095);
    const f16* f0p = featT + (((size_t)b * L_ + i0) << 6);
    const f16* f1p = featT + (((size_t)b * L_ + i1) << 6);

    // ---- W1 fragments ----
    const f16x8* W1p = (const f16x8*)W1f;
    f16x8 wb1[4][2];
    #pragma unroll
    for (int nt = 0; nt < 4; ++nt)
        #pragma unroll
        for (int ks = 0; ks < 2; ++ks)
            wb1[nt][ks] = W1p[(nt * 2 + ks) * 64 + l];

    // ---- A fragments: packed-f16 interpolated anchor features ----
    const f16 wh = (f16)w;
    f16x8 A1[2];
    #pragma unroll
    for (int ks = 0; ks < 2; ++ks) {
        const int ch = ks * 32 + q * 8;
        f16x8 u = *(const f16x8*)(f0p + ch);
        f16x8 v = *(const f16x8*)(f1p + ch);
        A1[ks] = u + splat8(wh) * (v - u);
    }

    // ---- layer 1: C init = b1 + cx*W1[64], then MFMA ----
    float cxr[4];
    #pragma unroll
    for (int reg = 0; reg < 4; ++reg) cxr[reg] = coords[p0 + q * 4 + reg];

    f32x4 Ch[4];
    #pragma unroll
    for (int nt = 0; nt < 4; ++nt) {
        const int hc = nt * 16 + col;
        const float bb = b1[hc];
        const float wl = W1[64 * 64 + hc];
        #pragma unroll
        for (int reg = 0; reg < 4; ++reg) Ch[nt][reg] = fmaf(cxr[reg], wl, bb);
    }
    #pragma unroll
    for (int nt = 0; nt < 4; ++nt)
        #pragma unroll
        for (int ks = 0; ks < 2; ++ks)
            Ch[nt] = mfma16(A1[ks], wb1[nt][ks], Ch[nt]);

    // ---- leaky -> a; stage to LDS ----
    #pragma unroll
    for (int nt = 0; nt < 4; ++nt)
        #pragma unroll
        for (int reg = 0; reg < 4; ++reg) {
            float hv = Ch[nt][reg];
            float av = hv >= 0.0f ? hv : NEG * hv;
            Ch[nt][reg] = av;
            a_tile[wv][q * 4 + reg][nt * 16 + col] = (f16)av;
        }

    // ---- residual: g = leaky(a + br + a@Wr), restage ----
    const f16x8* Wrp = (const f16x8*)Wrf;
    f16x8 wbr[4][2];
    #pragma unroll
    for (int nt = 0; nt < 4; ++nt)
        #pragma unroll
        for (int ks = 0; ks < 2; ++ks)
            wbr[nt][ks] = Wrp[(nt * 2 + ks) * 64 + l];

    f16x8 Ar[2];
    #pragma unroll
    for (int ks = 0; ks < 2; ++ks)
        Ar[ks] = *(const f16x8*)&a_tile[wv][r][ks * 32 + q * 8];

    f32x4 Cg[4];
    #pragma unroll
    for (int nt = 0; nt < 4; ++nt) {
        const float bb = br[nt * 16 + col];
        #pragma unroll
        for (int reg = 0; reg < 4; ++reg) Cg[nt][reg] = Ch[nt][reg] + bb;
        #pragma unroll
        for (int ks = 0; ks < 2; ++ks)
            Cg[nt] = mfma16(Ar[ks], wbr[nt][ks], Cg[nt]);
        #pragma unroll
        for (int reg = 0; reg < 4; ++reg) {
            float gv = Cg[nt][reg];
            gv = gv >= 0.0f ? gv : NEG * gv;
            a_tile[wv][q * 4 + reg][nt * 16 + col] = (f16)gv;
        }
    }

    // ---- layer 3: o = g @ W2pad + b2 ----
    const f16x8* W2p = (const f16x8*)W2f;
    f16x8 Ag[2];
    #pragma unroll
    for (int ks = 0; ks < 2; ++ks)
        Ag[ks] = *(const f16x8*)&a_tile[wv][r][ks * 32 + q * 8];

    const float b2v = (col < 10) ? b2[col] : 0.0f;
    f32x4 Co;
    #pragma unroll
    for (int reg = 0; reg < 4; ++reg) Co[reg] = b2v;
    #pragma unroll
    for (int ks = 0; ks < 2; ++ks)
        Co = mfma16(Ag[ks], W2p[ks * 64 + l], Co);

    // ---- epilogue: tanh offsets -> xq; softmax (no max-sub, f32-safe) -> wk ----
    const float maxoff = 6.0f / 4096.0f;
    const bool isSm = (col >= 5 && col < 10);
    #pragma unroll
    for (int reg = 0; reg < 4; ++reg) {
        const float ov = Co[reg];
        float e = isSm ? __expf(ov) : 0.0f;
        float s = e;
        #pragma unroll
        for (int d = 1; d < 16; d <<= 1) s += __shfl_xor(s, d, 16);
        const int pr = q * 4 + reg;
        const size_t pt = (size_t)(p0 + pr);
        if (col < 5) {
            float ax = fabsf(ov);
            float t = __expf(-2.0f * ax);
            float th = (1.0f - t) / (1.0f + t);
            float off = copysignf(th, ov) * maxoff;
            float dx = cxr[reg] + off;
            float xq = fminf(fmaxf((dx + 1.0f) * 0.5f * 4095.0f, 0.0f), 4095.0f);
            xq_arr[(size_t)col * P_ + pt] = xq;        // tap-major, stride-4B coalesced
        } else if (col < 10) {
            wk_arr[(size_t)(col - 5) * P_ + pt] = e / s;
        }
    }
}

// ---------- kernel 4: streaming gather + weighted aggregation ----------
// 4 lanes per point, 16 channels each; no LDS; packed-f16 math.
__global__ __launch_bounds__(256) void deform_agg(
    const f16* __restrict__ featT,
    const float* __restrict__ xq_arr, const float* __restrict__ wk_arr,
    float* __restrict__ out)
{
    const int idx = blockIdx.x * 256 + threadIdx.x;
    const int p = idx >> 2;
    const int q = idx & 3;
    const int b = p / N_;
    const size_t fb = (size_t)b * L_;

    float xq[5], wk[5];
    #pragma unroll
    for (int k = 0; k < 5; ++k) {
        xq[k] = xq_arr[(size_t)k * P_ + p];
        wk[k] = wk_arr[(size_t)k * P_ + p];
    }

    f16x8 acc0 = splat8((f16)0.0f);
    f16x8 acc1 = splat8((f16)0.0f);

    #pragma unroll
    for (int k = 0; k < 5; ++k) {
        float x0f = floorf(xq[k]);
        float wq = xq[k] - x0f;
        int j0 = (int)x0f;
        int j1 = min(j0 + 1, 4095);
        const f16* g0 = featT + ((fb + j0) << 6) + q * 16;
        const f16* g1 = featT + ((fb + j1) << 6) + q * 16;
        f16x8 u0 = *(const f16x8*)g0;
        f16x8 u1 = *(const f16x8*)(g0 + 8);
        f16x8 v0 = *(const f16x8*)g1;
        f16x8 v1 = *(const f16x8*)(g1 + 8);
        f16x8 wqv = splat8((f16)wq);
        f16x8 wkv = splat8((f16)wk[k]);
        acc0 += wkv * (u0 + wqv * (v0 - u0));
        acc1 += wkv * (u1 + wqv * (v1 - u1));
    }

    float* op = out + ((size_t)p << 6) + q * 16;
    f32x4 s0 = {(float)acc0[0], (float)acc0[1], (float)acc0[2], (float)acc0[3]};
    f32x4 s1 = {(float)acc0[4], (float)acc0[5], (float)acc0[6], (float)acc0[7]};
    f32x4 s2 = {(float)acc1[0], (float)acc1[1], (float)acc1[2], (float)acc1[3]};
    f32x4 s3 = {(float)acc1[4], (float)acc1[5], (float)acc1[6], (float)acc1[7]};
    __builtin_nontemporal_store(s0, (f32x4*)(op + 0));
    __builtin_nontemporal_store(s1, (f32x4*)(op + 4));
    __builtin_nontemporal_store(s2, (f32x4*)(op + 8));
    __builtin_nontemporal_store(s3, (f32x4*)(op + 12));
}

extern "C" void kernel_launch(void* const* d_in, const int* in_sizes, int n_in,
                              void* d_out, int out_size, void* d_ws, size_t ws_size,
                              hipStream_t stream) {
    const float* feat   = (const float*)d_in[0];
    const float* coords = (const float*)d_in[1];
    const float* W1 = (const float*)d_in[2];
    const float* b1 = (const float*)d_in[3];
    const float* Wr = (const float*)d_in[4];
    const float* br = (const float*)d_in[5];
    const float* W2 = (const float*)d_in[6];
    const float* b2 = (const float*)d_in[7];
    float* out = (float*)d_out;

    f16*   featT  = (f16*)d_ws;                              // 2 MiB
    f16*   W1f    = (f16*)((char*)d_ws + (2u << 20));        // 8 KiB
    f16*   Wrf    = W1f + 4096;                              // 8 KiB
    f16*   W2f    = Wrf + 4096;                              // 2 KiB
    float* xq_arr = (float*)((char*)d_ws + (4u << 20));      // 5*P*4 = 8 MB
    float* wk_arr = (float*)((char*)d_ws + (12u << 20));     // 8 MB

    hipLaunchKernelGGL(transpose_feat, dim3(L_ / 64, B_), dim3(256), 0, stream, feat, featT);
    hipLaunchKernelGGL(pack_weights, dim3(16), dim3(256), 0, stream, W1, Wr, W2, W1f, Wrf, W2f);
    hipLaunchKernelGGL(mlp_mfma, dim3(P_ / 64), dim3(256), 0, stream,
                       featT, coords, W1f, Wrf, W2f, W1, b1, br, b2, xq_arr, wk_arr);
    hipLaunchKernelGGL(deform_agg, dim3(P_ * 4 / 256), dim3(256), 0, stream,
                       featT, xq_arr, wk_arr, out);
}

// Round 9
// 218.433 us; speedup vs baseline: 1.0048x; 1.0048x over previous
//
#include <hip/hip_runtime.h>
#include <hip/hip_fp16.h>
#include <math.h>

typedef _Float16 f16;
typedef f16 f16x8 __attribute__((ext_vector_type(8)));
typedef float f32x4 __attribute__((ext_vector_type(4)));

#define B_ 4
#define C_ 64
#define L_ 4096
#define N_ 100000
#define P_ (B_ * N_)
#define NEG 0.2f

static __device__ __forceinline__ f32x4 mfma16(f16x8 a, f16x8 b, f32x4 c) {
    return __builtin_amdgcn_mfma_f32_16x16x32_f16(a, b, c, 0, 0, 0);
}
static __device__ __forceinline__ f16x8 splat8(f16 x) {
    f16x8 v = {x, x, x, x, x, x, x, x};
    return v;
}
// order LDS writes before subsequent cross-lane LDS reads (in-wave idiom hardening)
static __device__ __forceinline__ void lds_fence() {
    asm volatile("s_waitcnt lgkmcnt(0)" ::: "memory");
}

// ---------- kernel 1: transpose feat (B,C,L) f32 -> (B,L,C) f16 ----------
__global__ void transpose_feat(const float* __restrict__ src, f16* __restrict__ dst) {
    __shared__ float tile[64][65];
    const int b  = blockIdx.y;
    const int l0 = blockIdx.x * 64;
    const int tx = threadIdx.x & 63;
    const int ty = threadIdx.x >> 6;   // 0..3
    const size_t base = (size_t)b * C_ * L_;
    #pragma unroll
    for (int cc = ty; cc < 64; cc += 4)
        tile[cc][tx] = src[base + (size_t)cc * L_ + l0 + tx];
    __syncthreads();
    const int c2 = (threadIdx.x & 31) * 2;
    const int lh = (threadIdx.x >> 5) & 1;
    #pragma unroll
    for (int l8 = 0; l8 < 64; l8 += 8) {
        const int row = l8 + ty * 2 + lh;
        union { f16 h[2]; unsigned u; } pk;
        pk.h[0] = (f16)tile[c2][row];
        pk.h[1] = (f16)tile[c2 + 1][row];
        *(unsigned*)(dst + base + ((size_t)(l0 + row) << 6) + c2) = pk.u;
    }
}

// ---------- kernel 2: pack W1/Wr/W2 into per-lane f16 MFMA B-fragments ----------
__global__ void pack_weights(const float* __restrict__ W1, const float* __restrict__ Wr,
                             const float* __restrict__ W2,
                             f16* __restrict__ W1f, f16* __restrict__ Wrf, f16* __restrict__ W2f) {
    int i = blockIdx.x * 256 + threadIdx.x;
    if (i < 4096) {
        int e = i & 7, lane = (i >> 3) & 63, ks = (i >> 9) & 1, nt = i >> 10;
        int k = ks * 32 + (lane >> 4) * 8 + e;
        int c = nt * 16 + (lane & 15);
        W1f[i] = (f16)W1[k * 64 + c];
        Wrf[i] = (f16)Wr[k * 64 + c];
    }
    if (i < 1024) {                       // W2 padded 64x10 -> 64x16
        int e = i & 7, lane = (i >> 3) & 63, ks = (i >> 9) & 1;
        int k = ks * 32 + (lane >> 4) * 8 + e;
        int c = lane & 15;
        W2f[i] = (c < 10) ? (f16)W2[k * 10 + c] : (f16)0.0f;
    }
}

// ---------- kernel 3: router MLP via MFMA; writes tap-major xq / wk ----------
// one wave = 16 points. A-layout: lane -> row r=l&15, k=(l>>4)*8+e.
// C-layout (HW-verified): lane -> col=l&15, row=(l>>4)*4+reg.
__global__ __launch_bounds__(256) void mlp_mfma(
    const f16* __restrict__ featT, const float* __restrict__ coords,
    const f16* __restrict__ W1f, const f16* __restrict__ Wrf, const f16* __restrict__ W2f,
    const float* __restrict__ W1, const float* __restrict__ b1,
    const float* __restrict__ br, const float* __restrict__ b2,
    float* __restrict__ xq_arr, float* __restrict__ wk_arr)
{
    __shared__ __align__(16) f16 a_tile[4][16][72];   // per-wave staging

    const int tid = threadIdx.x;
    const int wv  = tid >> 6;
    const int l   = tid & 63;
    const int r   = l & 15;
    const int q   = l >> 4;
    const int col = l & 15;
    const int p0  = (blockIdx.x * 4 + wv) * 16;
    const int p   = p0 + r;
    const int b   = p / N_;

    // ---- anchor position for this lane's A-role point ----
    const float cx = coords[p];
    float xp = fminf(fmaxf((cx + 1.0f) * 0.5f * 4095.0f, 0.0f), 4095.0f);
    float x0f = floorf(xp);
    float w = xp - x0f;
    int i0 = (int)x0f;
    int i1 = min(i0 + 1, 4095);
    const f16* f0p = featT + (((size_t)b * L_ + i0) << 6);
    const f16* f1p = featT + (((size_t)b * L_ + i1) << 6);

    // ---- W1 fragments ----
    const f16x8* W1p = (const f16x8*)W1f;
    f16x8 wb1[4][2];
    #pragma unroll
    for (int nt = 0; nt < 4; ++nt)
        #pragma unroll
        for (int ks = 0; ks < 2; ++ks)
            wb1[nt][ks] = W1p[(nt * 2 + ks) * 64 + l];

    // ---- A fragments: packed-f16 interpolated anchor features ----
    const f16 wh = (f16)w;
    f16x8 A1[2];
    #pragma unroll
    for (int ks = 0; ks < 2; ++ks) {
        const int ch = ks * 32 + q * 8;
        f16x8 u = *(const f16x8*)(f0p + ch);
        f16x8 v = *(const f16x8*)(f1p + ch);
        A1[ks] = u + splat8(wh) * (v - u);
    }

    // ---- layer 1: C init = b1 + cx*W1[64], then MFMA ----
    float cxr[4];
    #pragma unroll
    for (int reg = 0; reg < 4; ++reg) cxr[reg] = coords[p0 + q * 4 + reg];

    f32x4 Ch[4];
    #pragma unroll
    for (int nt = 0; nt < 4; ++nt) {
        const int hc = nt * 16 + col;
        const float bb = b1[hc];
        const float wl = W1[64 * 64 + hc];
        #pragma unroll
        for (int reg = 0; reg < 4; ++reg) Ch[nt][reg] = fmaf(cxr[reg], wl, bb);
    }
    #pragma unroll
    for (int nt = 0; nt < 4; ++nt)
        #pragma unroll
        for (int ks = 0; ks < 2; ++ks)
            Ch[nt] = mfma16(A1[ks], wb1[nt][ks], Ch[nt]);

    // ---- leaky -> a; stage to LDS ----
    #pragma unroll
    for (int nt = 0; nt < 4; ++nt)
        #pragma unroll
        for (int reg = 0; reg < 4; ++reg) {
            float hv = Ch[nt][reg];
            float av = hv >= 0.0f ? hv : NEG * hv;
            Ch[nt][reg] = av;
            a_tile[wv][q * 4 + reg][nt * 16 + col] = (f16)av;
        }
    lds_fence();

    // ---- residual: g = leaky(a + br + a@Wr), restage ----
    const f16x8* Wrp = (const f16x8*)Wrf;
    f16x8 wbr[4][2];
    #pragma unroll
    for (int nt = 0; nt < 4; ++nt)
        #pragma unroll
        for (int ks = 0; ks < 2; ++ks)
            wbr[nt][ks] = Wrp[(nt * 2 + ks) * 64 + l];

    f16x8 Ar[2];
    #pragma unroll
    for (int ks = 0; ks < 2; ++ks)
        Ar[ks] = *(const f16x8*)&a_tile[wv][r][ks * 32 + q * 8];

    f32x4 Cg[4];
    #pragma unroll
    for (int nt = 0; nt < 4; ++nt) {
        const float bb = br[nt * 16 + col];
        #pragma unroll
        for (int reg = 0; reg < 4; ++reg) Cg[nt][reg] = Ch[nt][reg] + bb;
        #pragma unroll
        for (int ks = 0; ks < 2; ++ks)
            Cg[nt] = mfma16(Ar[ks], wbr[nt][ks], Cg[nt]);
        #pragma unroll
        for (int reg = 0; reg < 4; ++reg) {
            float gv = Cg[nt][reg];
            gv = gv >= 0.0f ? gv : NEG * gv;
            a_tile[wv][q * 4 + reg][nt * 16 + col] = (f16)gv;
        }
    }
    lds_fence();

    // ---- layer 3: o = g @ W2pad + b2 ----
    const f16x8* W2p = (const f16x8*)W2f;
    f16x8 Ag[2];
    #pragma unroll
    for (int ks = 0; ks < 2; ++ks)
        Ag[ks] = *(const f16x8*)&a_tile[wv][r][ks * 32 + q * 8];

    const float b2v = (col < 10) ? b2[col] : 0.0f;
    f32x4 Co;
    #pragma unroll
    for (int reg = 0; reg < 4; ++reg) Co[reg] = b2v;
    #pragma unroll
    for (int ks = 0; ks < 2; ++ks)
        Co = mfma16(Ag[ks], W2p[ks * 64 + l], Co);

    // ---- epilogue: tanh offsets -> xq; softmax (no max-sub, f32-safe) -> wk ----
    const float maxoff = 6.0f / 4096.0f;
    const bool isSm = (col >= 5 && col < 10);
    #pragma unroll
    for (int reg = 0; reg < 4; ++reg) {
        const float ov = Co[reg];
        float e = isSm ? __expf(ov) : 0.0f;
        float s = e;
        #pragma unroll
        for (int d = 1; d < 16; d <<= 1) s += __shfl_xor(s, d, 16);
        const int pr = q * 4 + reg;
        const size_t pt = (size_t)(p0 + pr);
        if (col < 5) {
            float ax = fabsf(ov);
            float t = __expf(-2.0f * ax);
            float th = (1.0f - t) / (1.0f + t);
            float off = copysignf(th, ov) * maxoff;
            float dx = cxr[reg] + off;
            float xq = fminf(fmaxf((dx + 1.0f) * 0.5f * 4095.0f, 0.0f), 4095.0f);
            xq_arr[(size_t)col * P_ + pt] = xq;        // tap-major, stride-4B coalesced
        } else if (col < 10) {
            wk_arr[(size_t)(col - 5) * P_ + pt] = e / s;
        }
    }
}

// ---------- kernel 4: streaming gather + weighted aggregation ----------
// 4 lanes per point, 16 channels each; all 20 gathers issued before the math.
__global__ __launch_bounds__(256) void deform_agg(
    const f16* __restrict__ featT,
    const float* __restrict__ xq_arr, const float* __restrict__ wk_arr,
    float* __restrict__ out)
{
    const int idx = blockIdx.x * 256 + threadIdx.x;
    const int p = idx >> 2;
    const int q = idx & 3;
    const int b = p / N_;
    const size_t fb = (size_t)b * L_;

    // phase 1: all (xq, wk)
    float xq[5], wk[5];
    #pragma unroll
    for (int k = 0; k < 5; ++k) {
        xq[k] = xq_arr[(size_t)k * P_ + p];
        wk[k] = wk_arr[(size_t)k * P_ + p];
    }

    // phase 2: all addresses
    float wq[5];
    const f16* g0p[5];
    const f16* g1p[5];
    #pragma unroll
    for (int k = 0; k < 5; ++k) {
        float x0f = floorf(xq[k]);
        wq[k] = xq[k] - x0f;
        int j0 = (int)x0f;
        int j1 = min(j0 + 1, 4095);
        g0p[k] = featT + ((fb + j0) << 6) + q * 16;
        g1p[k] = featT + ((fb + j1) << 6) + q * 16;
    }

    // phase 3: all 20 gather loads in flight
    f16x8 u0[5], u1[5], v0[5], v1[5];
    #pragma unroll
    for (int k = 0; k < 5; ++k) {
        u0[k] = *(const f16x8*)g0p[k];
        u1[k] = *(const f16x8*)(g0p[k] + 8);
        v0[k] = *(const f16x8*)g1p[k];
        v1[k] = *(const f16x8*)(g1p[k] + 8);
    }

    // phase 4: math (same accumulate order as round 5)
    f16x8 acc0 = splat8((f16)0.0f);
    f16x8 acc1 = splat8((f16)0.0f);
    #pragma unroll
    for (int k = 0; k < 5; ++k) {
        f16x8 wqv = splat8((f16)wq[k]);
        f16x8 wkv = splat8((f16)wk[k]);
        acc0 += wkv * (u0[k] + wqv * (v0[k] - u0[k]));
        acc1 += wkv * (u1[k] + wqv * (v1[k] - u1[k]));
    }

    float* op = out + ((size_t)p << 6) + q * 16;
    f32x4 s0 = {(float)acc0[0], (float)acc0[1], (float)acc0[2], (float)acc0[3]};
    f32x4 s1 = {(float)acc0[4], (float)acc0[5], (float)acc0[6], (float)acc0[7]};
    f32x4 s2 = {(float)acc1[0], (float)acc1[1], (float)acc1[2], (float)acc1[3]};
    f32x4 s3 = {(float)acc1[4], (float)acc1[5], (float)acc1[6], (float)acc1[7]};
    __builtin_nontemporal_store(s0, (f32x4*)(op + 0));
    __builtin_nontemporal_store(s1, (f32x4*)(op + 4));
    __builtin_nontemporal_store(s2, (f32x4*)(op + 8));
    __builtin_nontemporal_store(s3, (f32x4*)(op + 12));
}

extern "C" void kernel_launch(void* const* d_in, const int* in_sizes, int n_in,
                              void* d_out, int out_size, void* d_ws, size_t ws_size,
                              hipStream_t stream) {
    const float* feat   = (const float*)d_in[0];
    const float* coords = (const float*)d_in[1];
    const float* W1 = (const float*)d_in[2];
    const float* b1 = (const float*)d_in[3];
    const float* Wr = (const float*)d_in[4];
    const float* br = (const float*)d_in[5];
    const float* W2 = (const float*)d_in[6];
    const float* b2 = (const float*)d_in[7];
    float* out = (float*)d_out;

    f16*   featT  = (f16*)d_ws;                              // 2 MiB
    f16*   W1f    = (f16*)((char*)d_ws + (2u << 20));        // 8 KiB
    f16*   Wrf    = W1f + 4096;                              // 8 KiB
    f16*   W2f    = Wrf + 4096;                              // 2 KiB
    float* xq_arr = (float*)((char*)d_ws + (4u << 20));      // 5*P*4 = 8 MB
    float* wk_arr = (float*)((char*)d_ws + (12u << 20));     // 8 MB

    hipLaunchKernelGGL(transpose_feat, dim3(L_ / 64, B_), dim3(256), 0, stream, feat, featT);
    hipLaunchKernelGGL(pack_weights, dim3(16), dim3(256), 0, stream, W1, Wr, W2, W1f, Wrf, W2f);
    hipLaunchKernelGGL(mlp_mfma, dim3(P_ / 64), dim3(256), 0, stream,
                       featT, coords, W1f, Wrf, W2f, W1, b1, br, b2, xq_arr, wk_arr);
    hipLaunchKernelGGL(deform_agg, dim3(P_ * 4 / 256), dim3(256), 0, stream,
                       featT, xq_arr, wk_arr, out);
}